// Round 3
// baseline (120.182 us; speedup 1.0000x reference)
//
#include <hip/hip_runtime.h>
#include <hip/hip_bf16.h>

// LFQ forward fused kernels for MI355X (gfx950).
// Outputs in d_out (float32): out[16384*512], indices[16384] (as float), aux_loss[1]
// ws layout: T[4096][512] out-row table (8 MB) | P[512][4096] partials (8 MB)
//            | scal {C_sum, E_sum, done_count}

#define NS    16384      // samples = 4*4096
#define NOUT  (NS*512)   // 8388608
#define AUXO  (NOUT+NS)  // 8404992
#define INVT2 200.0f     // 2 * inv_temperature
#define NBLK  512        // K1 blocks; 32 samples each

// -------- K0: precompute all 4096 possible output rows.
// T[c][e] = b_out[e] + sum_d sg_d(c) * w_out[e][d], sg_d = +1 iff bit (11-d) of c set.
// FMA sequence mirrors the previous kernel's out-projection exactly (same s_wt
// swizzle, same float4 accumulate order) -> bitwise-identical `out`.
__global__ __launch_bounds__(512) void k_table(const float* __restrict__ w_out,
                                               const float* __restrict__ b_out,
                                               float* __restrict__ T) {
  __shared__ float s_wt[6144];   // f = d*512 + e holds w_out[e][d]
  const int t = threadIdx.x;
  #pragma unroll
  for (int k = 0; k < 12; ++k) s_wt[t + k * 512] = w_out[t * 12 + k];
  __syncthreads();

  const int c = blockIdx.x * 16 + (t >> 5);   // 16 codes per block, 4096 total
  float sg[12];
  #pragma unroll
  for (int d = 0; d < 12; ++d) sg[d] = ((c >> (11 - d)) & 1) ? 1.f : -1.f;

  float4* Trow = (float4*)(T + (size_t)c * 512);
  #pragma unroll
  for (int k4 = 0; k4 < 4; ++k4) {
    const int m = (t & 31) + k4 * 32;         // float4 index within the 512-row
    float4 bo = ((const float4*)b_out)[m];
    float4 o = bo;
    #pragma unroll
    for (int d = 0; d < 12; ++d) {
      float4 w4 = ((const float4*)s_wt)[d * 128 + m];
      o.x += sg[d] * w4.x; o.y += sg[d] * w4.y; o.z += sg[d] * w4.z; o.w += sg[d] * w4.w;
    }
    Trow[m] = o;
  }
}

// -------- K1: xp, indices, out-row gather, factorized softmax entropy + avg_prob partials
// One sample per 16-lane group; 4 samples/wave; 8 waves/block; 512 blocks.
// Dot partition / FMA order / shuffle tree identical to prior rounds -> xp bitwise identical.
__global__ __launch_bounds__(512, 4) void k_main(
    const float* __restrict__ x,
    const float* __restrict__ w_in,  const float* __restrict__ b_in,
    const float* __restrict__ T,
    float* __restrict__ out, float* __restrict__ idx_out,
    float* __restrict__ P, float* __restrict__ Csum) {

  __shared__ float s_wi[6144];      // w_in swizzled: [d][e4][sub] float4s (dot partition)
  __shared__ float s_phi[32][64];   // per-sample high-6-bit softmax probs
  __shared__ float s_psi[32][64];   // per-sample low-6-bit softmax probs
  __shared__ float s_xp[8][4][12];  // per-wave xp broadcast
  __shared__ float s_h[8];

  const int t = threadIdx.x;

  // stage w_in: element (d, e) with e = sub*32 + e4*4 + kk stored at
  //   f = ((d*128 + e4*16 + sub)*4 + kk) -> lane-sub b128 reads conflict-free.
  #pragma unroll
  for (int k = 0; k < 12; ++k) {
    int f  = t + k * 512;
    int kk = f & 3;
    int q  = f >> 2;
    int sub = q & 15, e4 = (q >> 4) & 7, d = q >> 7;
    int e  = sub * 32 + e4 * 4 + kk;
    s_wi[f] = w_in[d * 512 + e];
  }
  __syncthreads();

  const int wave = t >> 6, lane = t & 63;
  const int g = lane >> 4, sub = lane & 15;

  float bin[12];
  #pragma unroll
  for (int d = 0; d < 12; ++d) bin[d] = b_in[d];

  // ---- one sample per lane-group
  const int i0 = blockIdx.x * 32 + wave * 4 + g;

  const float4* xr0 = (const float4*)(x + (size_t)i0 * 512 + sub * 32);
  float4 xv0[8];
  #pragma unroll
  for (int e4 = 0; e4 < 8; ++e4) xv0[e4] = xr0[e4];

  // ---- partial dots for 12 dims
  float p0[12];
  #pragma unroll
  for (int d = 0; d < 12; ++d) p0[d] = 0.f;
  #pragma unroll
  for (int e4 = 0; e4 < 8; ++e4) {
    #pragma unroll
    for (int d = 0; d < 12; ++d) {
      float4 w4 = ((const float4*)s_wi)[d * 128 + e4 * 16 + sub];
      p0[d] += xv0[e4].x * w4.x + xv0[e4].y * w4.y + xv0[e4].z * w4.z + xv0[e4].w * w4.w;
    }
  }
  // ---- reduce across the 16 lanes of the sample (same tree -> bitwise equal)
  #pragma unroll
  for (int d = 0; d < 12; ++d) {
    #pragma unroll
    for (int m = 1; m <= 8; m <<= 1) {
      p0[d] += __shfl_xor(p0[d], m, 16);
    }
    p0[d] += bin[d];
  }

  // ---- indices (bit 11-d set iff xp_d > 0)
  unsigned idx0 = 0u;
  #pragma unroll
  for (int d = 0; d < 12; ++d) {
    idx0 |= (p0[d] > 0.f ? 1u : 0u) << (11 - d);
  }
  if (sub == 0) {
    idx_out[i0] = (float)idx0;
    #pragma unroll
    for (int d = 0; d < 12; ++d) s_xp[wave][g][d] = p0[d];
  }

  // ---- out row: pure gather of precomputed row T[idx0] (bitwise = old FMA path).
  // lane sub copies float4s e4*16+sub -> 256 contiguous bytes per group per instr.
  {
    const float4* Trow = (const float4*)(T + (size_t)idx0 * 512);
    float4* or0 = (float4*)(out + (size_t)i0 * 512);
    #pragma unroll
    for (int e4 = 0; e4 < 8; ++e4) {
      or0[e4 * 16 + sub] = Trow[e4 * 16 + sub];
    }
  }

  // ---- entropy: all 64 lanes process each of the wave's 4 samples
  float hacc = 0.f;
  #pragma unroll 1
  for (int s = 0; s < 4; ++s) {
    float xq[12];
    #pragma unroll
    for (int d = 0; d < 12; ++d) xq[d] = s_xp[wave][s][d];

    float hi = 0.f, lo = 0.f, ah = 0.f, al = 0.f;
    #pragma unroll
    for (int d = 0; d < 6; ++d) {
      int bh = (lane >> (5 - d)) & 1;
      hi += bh ? xq[d]     : -xq[d];
      lo += bh ? xq[6 + d] : -xq[6 + d];
      ah += fabsf(xq[d]);
      al += fabsf(xq[6 + d]);
    }
    float lhi = INVT2 * (hi - ah);   // <= 0, max over lanes == 0
    float llo = INVT2 * (lo - al);
    float ehi = __expf(lhi);
    float elo = __expf(llo);
    float Shi = ehi, Slo = elo;
    #pragma unroll
    for (int m = 1; m <= 32; m <<= 1) {
      Shi += __shfl_xor(Shi, m);
      Slo += __shfl_xor(Slo, m);
    }
    float phi = ehi / Shi;
    float psi = elo / Slo;
    float lnShi = __logf(Shi), lnSlo = __logf(Slo);
    // factorized per-sample entropy: H = -(sum phi log phi + sum psi log psi)
    hacc += phi * (lhi - lnShi) + psi * (llo - lnSlo);

    const int ws = wave * 4 + s;
    s_phi[ws][lane] = phi;
    s_psi[ws][lane] = psi;
  }

  // ---- per-sample-entropy: wave reduce, then block reduce
  #pragma unroll
  for (int m = 1; m <= 32; m <<= 1) hacc += __shfl_xor(hacc, m);
  if (lane == 0) s_h[wave] = hacc;
  __syncthreads();   // also publishes s_phi/s_psi for phase B
  if (t == 0) {
    float hs = 0.f;
    for (int w2 = 0; w2 < 8; ++w2) hs += s_h[w2];
    atomicAdd(Csum, hs);
  }

  // ---- phase B: avg_prob partial P[j][l] = sum_s phi[s][j]*psi[s][l]
  // each thread owns a 4(j) x 2(l) code tile -> 8 accumulator registers
  const int jb = (t >> 5) * 4;   // 16 j-tiles of 4
  const int lb = (t & 31) * 2;   // 32 l-tiles of 2
  float a00 = 0.f, a01 = 0.f, a10 = 0.f, a11 = 0.f;
  float a20 = 0.f, a21 = 0.f, a30 = 0.f, a31 = 0.f;
  #pragma unroll 4
  for (int s = 0; s < 32; ++s) {
    float4 ph = *(const float4*)&s_phi[s][jb];
    float2 ps = *(const float2*)&s_psi[s][lb];
    a00 += ph.x * ps.x; a01 += ph.x * ps.y;
    a10 += ph.y * ps.x; a11 += ph.y * ps.y;
    a20 += ph.z * ps.x; a21 += ph.z * ps.y;
    a30 += ph.w * ps.x; a31 += ph.w * ps.y;
  }
  float* Pr = P + (size_t)blockIdx.x * 4096;
  *(float2*)&Pr[(jb + 0) * 64 + lb] = make_float2(a00, a01);
  *(float2*)&Pr[(jb + 1) * 64 + lb] = make_float2(a10, a11);
  *(float2*)&Pr[(jb + 2) * 64 + lb] = make_float2(a20, a21);
  *(float2*)&Pr[(jb + 3) * 64 + lb] = make_float2(a30, a31);
}

// -------- K2: reduce partials -> avg_prob, codebook entropy; last block emits aux_loss
__global__ __launch_bounds__(256) void k_reduce(const float* __restrict__ P,
                                                float* __restrict__ scal,
                                                float* __restrict__ aux) {
  __shared__ float red[16][17];
  __shared__ float ered[16];
  const int t = threadIdx.x;
  const int cl = t & 15, rg = t >> 4;
  const int c = blockIdx.x * 16 + cl;
  float s = 0.f;
  #pragma unroll
  for (int k = 0; k < 32; ++k) s += P[(size_t)(rg + k * 16) * 4096 + c];
  red[rg][cl] = s;
  __syncthreads();
  if (t < 16) {
    float tot = 0.f;
    #pragma unroll
    for (int r = 0; r < 16; ++r) tot += red[r][t];
    float pb = tot * (1.f / (float)NS);
    ered[t] = pb * __logf(fmaxf(pb, 1e-5f));   // p * log(clip(p, eps))
  }
  __syncthreads();
  if (t == 0) {
    float e = 0.f;
    #pragma unroll
    for (int r = 0; r < 16; ++r) e += ered[r];
    atomicAdd(&scal[1], e);
    __threadfence();
    unsigned done = atomicAdd((unsigned*)&scal[2], 1u);
    if (done == 255u) {   // last of 256 blocks: fold in the final combine (was K3)
      float E = atomicAdd(&scal[1], 0.f);   // coherent reads via atomic
      float C = atomicAdd(&scal[0], 0.f);
      float per_sample_entropy = -C * (1.f / (float)NS);
      float codebook_entropy   = -E;
      aux[0] = 0.1f * (per_sample_entropy - codebook_entropy);
    }
  }
}

extern "C" void kernel_launch(void* const* d_in, const int* in_sizes, int n_in,
                              void* d_out, int out_size, void* d_ws, size_t ws_size,
                              hipStream_t stream) {
  const float* x     = (const float*)d_in[0];
  const float* w_in  = (const float*)d_in[1];
  const float* b_in  = (const float*)d_in[2];
  const float* w_out = (const float*)d_in[3];
  const float* b_out = (const float*)d_in[4];
  float* out = (float*)d_out;

  float* T    = (float*)d_ws;                                   // 4096*512 f32 = 8 MB
  float* P    = T + (size_t)4096 * 512;                         // 512*4096 f32 = 8 MB
  float* scal = P + (size_t)NBLK * 4096;                        // {C_sum, E_sum, done}

  hipMemsetAsync(scal, 0, 3 * sizeof(float), stream);
  k_table<<<256, 512, 0, stream>>>(w_out, b_out, T);
  k_main<<<NBLK, 512, 0, stream>>>(x, w_in, b_in, T,
                                   out, out + NOUT, P, scal);
  k_reduce<<<256, 256, 0, stream>>>(P, scal, out + AUXO);
}